// Round 9
// baseline (538.050 us; speedup 1.0000x reference)
//
#include <hip/hip_runtime.h>
#include <hip/hip_bf16.h>
#include <hip/hip_cooperative_groups.h>

namespace cg = cooperative_groups;

#define NN 10000
#define NE 640000
#define D_IN 128
#define D_H 128
#define N_CLS 64
#define CAP 160    // per-node capacity (ushort): mean 64 sigma 8 -> +12 sigma
#define GRP 157    // coarse groups: dst>>6 (64 nodes/group)
#define CAPC 4800  // per-group coarse capacity
#define CCS 16     // coarse_cnt stride (ints): one counter per 64B line
#define SENT 10000 // sentinel node id (zero row)
#define EPB 1024
#define AB 625     // 625*1024 == 640000
#define W01B 16    // blocks computing W01 = W0@W1 (f32)
#define WPB 4      // prep_b blocks packing Wp = W01@W2 (bf16 k-pairs)
#define CGRID 1024 // cooperative grid (4 blocks/CU x 256 CUs)
#define NBLK (NN / 4)

// ---- bf16 helpers ----
__device__ __forceinline__ float blo(unsigned u) { return __uint_as_float(u << 16); }
__device__ __forceinline__ float bhi(unsigned u) { return __uint_as_float(u & 0xffff0000u); }
__device__ __forceinline__ unsigned short f2bf(float f) {
    unsigned u = __float_as_uint(f);
    return (unsigned short)((u + 0x7fffu + ((u >> 16) & 1u)) >> 16);
}
__device__ __forceinline__ unsigned packbf(float a, float b) {
    return (unsigned)f2bf(a) | ((unsigned)f2bf(b) << 16);
}

// ---- prep_a: coarse-bucket edges + W01 = W0@W1 (f32) ----
__global__ __launch_bounds__(256) void prep_a(const int* __restrict__ src,
                                              const int* __restrict__ dst,
                                              int* __restrict__ coarse_cnt,
                                              unsigned* __restrict__ coarse,
                                              const float* __restrict__ W0,
                                              const float* __restrict__ W1,
                                              float* __restrict__ W01) {
    int bid = blockIdx.x;
    if (bid >= AB) {   // ---- W01 = W0@W1, f32 (16 blocks x 256 thr, 4 cols each) ----
        int t = (bid - AB) * 256 + threadIdx.x;   // 0..4095
        int i = t >> 5;            // row 0..127
        int jb = (t & 31) << 2;    // col group of 4
        float c0 = 0.f, c1 = 0.f, c2 = 0.f, c3 = 0.f;
        for (int k = 0; k < 128; ++k) {
            float a = W0[i * 128 + k];
            float4 b = *(const float4*)&W1[k * 128 + jb];
            c0 += a * b.x; c1 += a * b.y; c2 += a * b.z; c3 += a * b.w;
        }
        *(float4*)&W01[i * 128 + jb] = make_float4(c0, c1, c2, c3);
        return;
    }
    __shared__ unsigned stage[EPB];
    __shared__ int hist[GRP], gbase[GRP], cur[GRP];
    const int t = threadIdx.x;
    for (int i = t; i < GRP; i += 256) hist[i] = 0;
    __syncthreads();
    const int e0 = bid * EPB;
    for (int i = t; i < EPB; i += 256) {
        int s = src[e0 + i];
        int d = dst[e0 + i];
        stage[i] = (unsigned)s | ((unsigned)d << 16);
        atomicAdd(&hist[d >> 6], 1);
    }
    __syncthreads();
    for (int i = t; i < GRP; i += 256) {
        gbase[i] = atomicAdd(&coarse_cnt[i * CCS], hist[i]);
        cur[i] = 0;
    }
    __syncthreads();
    for (int i = t; i < EPB; i += 256) {
        unsigned u = stage[i];
        int g = u >> 22;
        int r = atomicAdd(&cur[g], 1);
        coarse[g * CAPC + gbase[g] + r] = u;
    }
}

// ---- prep_b: per-group scatter into LDS-staged colbuf (pad to x32) + Wp pack ----
__global__ __launch_bounds__(1024) void prep_b(const int* __restrict__ coarse_cnt,
                                               const unsigned* __restrict__ coarse,
                                               int* __restrict__ cnt,
                                               unsigned short* __restrict__ colbuf,
                                               const float* __restrict__ W01,
                                               const float* __restrict__ W2,
                                               unsigned* __restrict__ wbp) {
    const int g = blockIdx.x;
    const int t = threadIdx.x;
    if (g >= GRP) {   // ---- Wp pack: 4 blocks x 1024 thr = 4096 pack-slots (kp,j) ----
        int s = (g - GRP) * 1024 + t;   // 0..4095
        int kp = s >> 6, j = s & 63;
        float c0 = 0.f, c1 = 0.f;
        const float* r0 = W01 + (2 * kp) * 128;
        const float* r1 = r0 + 128;
        for (int k = 0; k < 128; ++k) {
            float w2 = W2[k * 64 + j];
            c0 += r0[k] * w2;
            c1 += r1[k] * w2;
        }
        wbp[kp * 64 + j] = packbf(c0, c1);
        return;
    }
    __shared__ int cur[64];
    __shared__ unsigned short sbuf[64][CAP];   // 20480 B LDS stage for this group
    if (t < 64) cur[t] = 0;
    __syncthreads();
    const int m = coarse_cnt[g * CCS];
    const unsigned* cb = coarse + g * CAPC;
    for (int i = t; i < m; i += 1024) {
        unsigned u = cb[i];
        int s = (int)(u & 0xFFFFu);
        int dl = (int)(u >> 16) - (g << 6);
        int r = atomicAdd(&cur[dl], 1);
        sbuf[dl][r] = (unsigned short)s;       // 2B scatter stays in LDS
    }
    __syncthreads();
    if (t < 64) {
        int n = (g << 6) + t;
        if (n < NN) {
            int c = cur[t];
            int pad = (32 - (c & 31)) & 31;    // pad to x32 for the unrolled gather
            for (int k = 0; k < pad; ++k) sbuf[t][c + k] = (unsigned short)SENT;
            cnt[n] = c + pad;
        }
    }
    __syncthreads();
    // coalesced copy-out: 64 nodes x (CAP/8 = 20) uint4
    const uint4* s4 = (const uint4*)sbuf;
    for (int idx = t; idx < 64 * (CAP / 8); idx += 1024) {
        int node = (g << 6) + (idx / (CAP / 8));
        if (node < NN)
            ((uint4*)colbuf)[(size_t)node * (CAP / 8) + (idx % (CAP / 8))] = s4[idx];
    }
}

// ---- dense projection step: g0_row(n) = feat_row(n) @ Wp ----
__device__ __forceinline__ void gemm0_step(const float* __restrict__ feat,
                                           const unsigned* __restrict__ Wbp,
                                           unsigned short* __restrict__ g0,
                                           float xsrow[128],
                                           int n, int lane) {
    float2 f = *(const float2*)&feat[(size_t)n * 128 + lane * 2];
    xsrow[lane * 2]     = f.x;
    xsrow[lane * 2 + 1] = f.y;   // same-wave write->read: no block barrier needed
    float acc = 0.f;
    for (int k = 0; k < 128; k += 4) {
        unsigned wp0 = Wbp[(k >> 1) * 64 + lane];
        unsigned wp1 = Wbp[((k >> 1) + 1) * 64 + lane];
        float4 xv = *(const float4*)&xsrow[k];
        acc += xv.x * blo(wp0) + xv.y * bhi(wp0) + xv.z * blo(wp1) + xv.w * bhi(wp1);
    }
    g0[(size_t)n * 64 + lane] = f2bf(acc);
}

// ---- 64-d aggregate step (32-row chunks) ----
template <bool LAST>
__device__ __forceinline__ void agg_step(const uint4* __restrict__ in4,
                                         const int* __restrict__ cnt,
                                         const unsigned short* __restrict__ colbuf,
                                         unsigned short* __restrict__ outb,
                                         float* __restrict__ outf,
                                         int blk, int wave, int lane) {
    const int sub = lane >> 3;     // 0..7 : 8 rows per load instruction
    const int off = lane & 7;      // 16B slice within a 128B row
    const int n = __builtin_amdgcn_readfirstlane(blk * 4 + wave);
    float a0, a1, a2, a3, a4, a5, a6, a7;
    if (sub == 0) {                // own row (eps=0)
        uint4 u = in4[n * 8 + off];
        a0 = blo(u.x); a1 = bhi(u.x); a2 = blo(u.y); a3 = bhi(u.y);
        a4 = blo(u.z); a5 = bhi(u.z); a6 = blo(u.w); a7 = bhi(u.w);
    } else {
        a0 = a1 = a2 = a3 = a4 = a5 = a6 = a7 = 0.f;
    }
    const int NCH = __builtin_amdgcn_readfirstlane(cnt[n]) >> 5;   // 32-row chunks
    const uint2* cl = (const uint2*)(colbuf + (size_t)n * CAP);
    const int hi4 = sub >> 2;
    const int wsel = (sub >> 1) & 1;
    const int sh = (sub & 1) << 4;
    uint2 p0 = cl[0], p1 = cl[1], p2 = cl[2], p3 = cl[3];
    uint2 p4 = cl[4], p5 = cl[5], p6 = cl[6], p7 = cl[7];
    for (int c = 0; c < NCH; ++c) {
        unsigned q0 = hi4 ? (wsel ? p1.y : p1.x) : (wsel ? p0.y : p0.x);
        unsigned q1 = hi4 ? (wsel ? p3.y : p3.x) : (wsel ? p2.y : p2.x);
        unsigned q2 = hi4 ? (wsel ? p5.y : p5.x) : (wsel ? p4.y : p4.x);
        unsigned q3 = hi4 ? (wsel ? p7.y : p7.x) : (wsel ? p6.y : p6.x);
        int s0 = (int)((q0 >> sh) & 0xffffu);
        int s1 = (int)((q1 >> sh) & 0xffffu);
        int s2 = (int)((q2 >> sh) & 0xffffu);
        int s3 = (int)((q3 >> sh) & 0xffffu);
        uint4 u0 = in4[s0 * 8 + off];
        uint4 u1 = in4[s1 * 8 + off];
        uint4 u2 = in4[s2 * 8 + off];
        uint4 u3 = in4[s3 * 8 + off];
        {
            const uint2* nx = cl + 8 * (c + 1);   // safe over-read within workspace
            p0 = nx[0]; p1 = nx[1]; p2 = nx[2]; p3 = nx[3];
            p4 = nx[4]; p5 = nx[5]; p6 = nx[6]; p7 = nx[7];
        }
        a0 += (blo(u0.x) + blo(u1.x)) + (blo(u2.x) + blo(u3.x));
        a1 += (bhi(u0.x) + bhi(u1.x)) + (bhi(u2.x) + bhi(u3.x));
        a2 += (blo(u0.y) + blo(u1.y)) + (blo(u2.y) + blo(u3.y));
        a3 += (bhi(u0.y) + bhi(u1.y)) + (bhi(u2.y) + bhi(u3.y));
        a4 += (blo(u0.z) + blo(u1.z)) + (blo(u2.z) + blo(u3.z));
        a5 += (bhi(u0.z) + bhi(u1.z)) + (bhi(u2.z) + bhi(u3.z));
        a6 += (blo(u0.w) + blo(u1.w)) + (blo(u2.w) + blo(u3.w));
        a7 += (bhi(u0.w) + bhi(u1.w)) + (bhi(u2.w) + bhi(u3.w));
    }
    a0 += __shfl_xor(a0, 8); a0 += __shfl_xor(a0, 16); a0 += __shfl_xor(a0, 32);
    a1 += __shfl_xor(a1, 8); a1 += __shfl_xor(a1, 16); a1 += __shfl_xor(a1, 32);
    a2 += __shfl_xor(a2, 8); a2 += __shfl_xor(a2, 16); a2 += __shfl_xor(a2, 32);
    a3 += __shfl_xor(a3, 8); a3 += __shfl_xor(a3, 16); a3 += __shfl_xor(a3, 32);
    a4 += __shfl_xor(a4, 8); a4 += __shfl_xor(a4, 16); a4 += __shfl_xor(a4, 32);
    a5 += __shfl_xor(a5, 8); a5 += __shfl_xor(a5, 16); a5 += __shfl_xor(a5, 32);
    a6 += __shfl_xor(a6, 8); a6 += __shfl_xor(a6, 16); a6 += __shfl_xor(a6, 32);
    a7 += __shfl_xor(a7, 8); a7 += __shfl_xor(a7, 16); a7 += __shfl_xor(a7, 32);
    if (sub == 0) {
        if (LAST) {
            float* o = outf + (size_t)n * N_CLS + 8 * off;
            *(float4*)o       = make_float4(a0, a1, a2, a3);
            *(float4*)(o + 4) = make_float4(a4, a5, a6, a7);
        } else {
            unsigned short* o = outb + (size_t)n * 64 + 8 * off;
            *(uint4*)o = make_uint4(packbf(a0, a1), packbf(a2, a3),
                                    packbf(a4, a5), packbf(a6, a7));
        }
    }
}

// ---- standalone kernels (fallback path, identical to verified R5) ----
__global__ __launch_bounds__(256, 4) void gemm0(const float* __restrict__ feat,
                                                const unsigned* __restrict__ Wbp,
                                                unsigned short* __restrict__ g0) {
    __shared__ float xs[4][128];
    const int tid = threadIdx.x;
    const int wave = tid >> 6;
    const int lane = tid & 63;
    gemm0_step(feat, Wbp, g0, xs[wave], blockIdx.x * 4 + wave, lane);
    if (blockIdx.x == 0 && tid < 16) {
        ((uint2*)(g0 + (size_t)SENT * 64))[tid] = make_uint2(0u, 0u);
    }
}

__global__ __launch_bounds__(256, 4) void agg64b(const uint4* __restrict__ tb4,
                                                 const int* __restrict__ cnt,
                                                 const unsigned short* __restrict__ colbuf,
                                                 unsigned short* __restrict__ tb2) {
    const int tid = threadIdx.x;
    agg_step<false>(tb4, cnt, colbuf, tb2, nullptr, blockIdx.x, tid >> 6, tid & 63);
    if (blockIdx.x == 0 && tid < 16) {
        ((uint2*)(tb2 + (size_t)SENT * 64))[tid] = make_uint2(0u, 0u);
    }
}

__global__ __launch_bounds__(256, 4) void agg64f(const uint4* __restrict__ tb4,
                                                 const int* __restrict__ cnt,
                                                 const unsigned short* __restrict__ colbuf,
                                                 float* __restrict__ outf) {
    const int tid = threadIdx.x;
    agg_step<true>(tb4, cnt, colbuf, nullptr, outf, blockIdx.x, tid >> 6, tid & 63);
}

// ---- mega: gemm0 + 3 aggregates, single cooperative launch, 3 grid syncs ----
__global__ __launch_bounds__(256, 4) void mega(const float* __restrict__ feat,
                                               const unsigned* __restrict__ Wbp,
                                               unsigned short* __restrict__ g0,
                                               const int* __restrict__ cnt,
                                               const unsigned short* __restrict__ colbuf,
                                               unsigned short* __restrict__ tb,
                                               unsigned short* __restrict__ tb2,
                                               float* __restrict__ outf) {
    cg::grid_group grid = cg::this_grid();
    __shared__ float xs[4][128];
    const int tid = threadIdx.x;
    const int wave = tid >> 6;
    const int lane = tid & 63;

    for (int blk = blockIdx.x; blk < NBLK; blk += CGRID)
        gemm0_step(feat, Wbp, g0, xs[wave], blk * 4 + wave, lane);
    if (blockIdx.x == 0 && tid < 16)
        ((uint2*)(g0 + (size_t)SENT * 64))[tid] = make_uint2(0u, 0u);
    grid.sync();

    for (int blk = blockIdx.x; blk < NBLK; blk += CGRID)
        agg_step<false>((const uint4*)g0, cnt, colbuf, tb, nullptr, blk, wave, lane);
    if (blockIdx.x == 0 && tid < 16)
        ((uint2*)(tb + (size_t)SENT * 64))[tid] = make_uint2(0u, 0u);
    grid.sync();

    for (int blk = blockIdx.x; blk < NBLK; blk += CGRID)
        agg_step<false>((const uint4*)tb, cnt, colbuf, tb2, nullptr, blk, wave, lane);
    if (blockIdx.x == 0 && tid < 16)
        ((uint2*)(tb2 + (size_t)SENT * 64))[tid] = make_uint2(0u, 0u);
    grid.sync();

    for (int blk = blockIdx.x; blk < NBLK; blk += CGRID)
        agg_step<true>((const uint4*)tb2, cnt, colbuf, nullptr, outf, blk, wave, lane);
}

extern "C" void kernel_launch(void* const* d_in, const int* in_sizes, int n_in,
                              void* d_out, int out_size, void* d_ws, size_t ws_size,
                              hipStream_t stream) {
    const float* feat = (const float*)d_in[0];
    const float* W0   = (const float*)d_in[1];
    const float* W1   = (const float*)d_in[2];
    const float* W2   = (const float*)d_in[3];
    const int*   src  = (const int*)d_in[4];
    const int*   dst  = (const int*)d_in[5];
    float* out = (float*)d_out;

    int* coarse_cnt        = (int*)d_ws;                          // GRP*CCS ints
    int* cnt               = coarse_cnt + GRP * CCS;              // NN (+8 align pad)
    unsigned short* colbuf = (unsigned short*)(cnt + NN + 8);     // NN*CAP
    unsigned* coarse       = (unsigned*)(colbuf + (size_t)NN * CAP);  // GRP*CAPC
    unsigned* g0u          = coarse + (size_t)GRP * CAPC;         // (NN+1)*32 (64-d bf16)
    unsigned* tbu          = g0u + (size_t)(NN + 1) * 32;         // (NN+1)*32
    unsigned* tb2u         = tbu + (size_t)(NN + 1) * 32;         // (NN+1)*32
    float* W01             = (float*)(tb2u + (size_t)(NN + 1) * 32); // 16384 f32
    unsigned* wbp          = (unsigned*)(W01 + 16384);            // 4096
    unsigned short* g0     = (unsigned short*)g0u;
    unsigned short* tb     = (unsigned short*)tbu;
    unsigned short* tb2    = (unsigned short*)tb2u;

    (void)hipMemsetAsync(coarse_cnt, 0, GRP * CCS * sizeof(int), stream);
    prep_a<<<AB + W01B, 256, 0, stream>>>(src, dst, coarse_cnt, coarse, W0, W1, W01);
    prep_b<<<GRP + WPB, 1024, 0, stream>>>(coarse_cnt, coarse, cnt, colbuf,
                                           W01, W2, wbp);

    // ---- try cooperative fusion; on any launch error fall back to 4 kernels ----
    const float* feat_ = feat;
    const unsigned* wbp_ = wbp;
    unsigned short* g0_ = g0;
    const int* cnt_ = cnt;
    const unsigned short* colbuf_ = colbuf;
    unsigned short* tb_ = tb;
    unsigned short* tb2_ = tb2;
    float* out_ = out;
    void* kargs[] = {(void*)&feat_, (void*)&wbp_, (void*)&g0_, (void*)&cnt_,
                     (void*)&colbuf_, (void*)&tb_, (void*)&tb2_, (void*)&out_};
    hipError_t ce = hipLaunchCooperativeKernel((void*)mega, dim3(CGRID), dim3(256),
                                               kargs, 0, stream);
    if (ce != hipSuccess) {
        gemm0<<<NBLK, 256, 0, stream>>>(feat, wbp, g0);
        agg64b<<<NBLK, 256, 0, stream>>>((const uint4*)g0, cnt, colbuf, tb);
        agg64b<<<NBLK, 256, 0, stream>>>((const uint4*)tb, cnt, colbuf, tb2);
        agg64f<<<NBLK, 256, 0, stream>>>((const uint4*)tb2, cnt, colbuf, out);
    }
}

// Round 10
// 137.217 us; speedup vs baseline: 3.9212x; 3.9212x over previous
//
#include <hip/hip_runtime.h>
#include <hip/hip_bf16.h>

#define NN 10000
#define NE 640000
#define D_IN 128
#define D_H 128
#define N_CLS 64
#define CAP 160    // per-node capacity (ushort): mean 64 sigma 8 -> +12 sigma
#define GRP 157    // coarse groups: dst>>6 (64 nodes/group)
#define CAPC 4800  // per-group coarse capacity
#define CCS 16     // coarse_cnt stride (ints): one counter per 64B line
#define SENT 10000 // sentinel node id (zero row)
#define EPB 1024
#define AB 625     // 625*1024 == 640000
#define W01B 16    // blocks computing W01 = W0@W1 (f32)
#define WPB 4      // prep_b blocks packing Wp = W01@W2 (bf16 k-pairs)

// ---- bf16 helpers ----
__device__ __forceinline__ float blo(unsigned u) { return __uint_as_float(u << 16); }
__device__ __forceinline__ float bhi(unsigned u) { return __uint_as_float(u & 0xffff0000u); }
__device__ __forceinline__ unsigned short f2bf(float f) {
    unsigned u = __float_as_uint(f);
    return (unsigned short)((u + 0x7fffu + ((u >> 16) & 1u)) >> 16);
}
__device__ __forceinline__ unsigned packbf(float a, float b) {
    return (unsigned)f2bf(a) | ((unsigned)f2bf(b) << 16);
}

// ---- prep_a: coarse-bucket edges + W01 = W0@W1 (f32) ----
__global__ __launch_bounds__(256) void prep_a(const int* __restrict__ src,
                                              const int* __restrict__ dst,
                                              int* __restrict__ coarse_cnt,
                                              unsigned* __restrict__ coarse,
                                              const float* __restrict__ W0,
                                              const float* __restrict__ W1,
                                              float* __restrict__ W01) {
    int bid = blockIdx.x;
    if (bid >= AB) {   // ---- W01 = W0@W1, f32 (16 blocks x 256 thr, 4 cols each) ----
        int t = (bid - AB) * 256 + threadIdx.x;   // 0..4095
        int i = t >> 5;            // row 0..127
        int jb = (t & 31) << 2;    // col group of 4
        float c0 = 0.f, c1 = 0.f, c2 = 0.f, c3 = 0.f;
        for (int k = 0; k < 128; ++k) {
            float a = W0[i * 128 + k];
            float4 b = *(const float4*)&W1[k * 128 + jb];
            c0 += a * b.x; c1 += a * b.y; c2 += a * b.z; c3 += a * b.w;
        }
        *(float4*)&W01[i * 128 + jb] = make_float4(c0, c1, c2, c3);
        return;
    }
    __shared__ unsigned stage[EPB];
    __shared__ int hist[GRP], gbase[GRP], cur[GRP];
    const int t = threadIdx.x;
    for (int i = t; i < GRP; i += 256) hist[i] = 0;
    __syncthreads();
    const int e0 = bid * EPB;
    for (int i = t; i < EPB; i += 256) {
        int s = src[e0 + i];
        int d = dst[e0 + i];
        stage[i] = (unsigned)s | ((unsigned)d << 16);
        atomicAdd(&hist[d >> 6], 1);
    }
    __syncthreads();
    for (int i = t; i < GRP; i += 256) {
        gbase[i] = atomicAdd(&coarse_cnt[i * CCS], hist[i]);
        cur[i] = 0;
    }
    __syncthreads();
    for (int i = t; i < EPB; i += 256) {
        unsigned u = stage[i];
        int g = u >> 22;
        int r = atomicAdd(&cur[g], 1);
        coarse[g * CAPC + gbase[g] + r] = u;
    }
}

// ---- prep_b: per-group scatter into LDS-staged colbuf (pad to x32) + Wp pack ----
__global__ __launch_bounds__(1024) void prep_b(const int* __restrict__ coarse_cnt,
                                               const unsigned* __restrict__ coarse,
                                               int* __restrict__ cnt,
                                               unsigned short* __restrict__ colbuf,
                                               const float* __restrict__ W01,
                                               const float* __restrict__ W2,
                                               unsigned* __restrict__ wbp) {
    const int g = blockIdx.x;
    const int t = threadIdx.x;
    if (g >= GRP) {   // ---- Wp pack: 4 blocks x 1024 thr = 4096 pack-slots (kp,j) ----
        int s = (g - GRP) * 1024 + t;   // 0..4095
        int kp = s >> 6, j = s & 63;
        float c0 = 0.f, c1 = 0.f;
        const float* r0 = W01 + (2 * kp) * 128;
        const float* r1 = r0 + 128;
        for (int k = 0; k < 128; ++k) {
            float w2 = W2[k * 64 + j];
            c0 += r0[k] * w2;
            c1 += r1[k] * w2;
        }
        wbp[kp * 64 + j] = packbf(c0, c1);
        return;
    }
    __shared__ int cur[64];
    __shared__ unsigned short sbuf[64][CAP];   // 20480 B LDS stage for this group
    if (t < 64) cur[t] = 0;
    __syncthreads();
    const int m = coarse_cnt[g * CCS];
    const unsigned* cb = coarse + g * CAPC;
    for (int i = t; i < m; i += 1024) {
        unsigned u = cb[i];
        int s = (int)(u & 0xFFFFu);
        int dl = (int)(u >> 16) - (g << 6);
        int r = atomicAdd(&cur[dl], 1);
        sbuf[dl][r] = (unsigned short)s;       // 2B scatter stays in LDS
    }
    __syncthreads();
    if (t < 64) {
        int n = (g << 6) + t;
        if (n < NN) {
            int c = cur[t];
            int pad = (32 - (c & 31)) & 31;    // pad to x32 for the unrolled gather
            for (int k = 0; k < pad; ++k) sbuf[t][c + k] = (unsigned short)SENT;
            cnt[n] = c + pad;
        }
    }
    __syncthreads();
    // coalesced copy-out: 64 nodes x (CAP/8 = 20) uint4
    const uint4* s4 = (const uint4*)sbuf;
    for (int idx = t; idx < 64 * (CAP / 8); idx += 1024) {
        int node = (g << 6) + (idx / (CAP / 8));
        if (node < NN)
            ((uint4*)colbuf)[(size_t)node * (CAP / 8) + (idx % (CAP / 8))] = s4[idx];
    }
}

// ---- gemm0: g0 = feat @ Wp (dense, coalesced; 128 -> 64, bf16 out) ----
__global__ __launch_bounds__(256, 4) void gemm0(const float* __restrict__ feat,
                                                const unsigned* __restrict__ Wbp,
                                                unsigned short* __restrict__ g0) {
    __shared__ float xs[4][128];
    const int tid = threadIdx.x;
    const int wave = tid >> 6;
    const int lane = tid & 63;
    const int n = blockIdx.x * 4 + wave;
    float2 f = *(const float2*)&feat[(size_t)n * 128 + lane * 2];
    xs[wave][lane * 2]     = f.x;
    xs[wave][lane * 2 + 1] = f.y;
    __syncthreads();
    const int j = lane;
    float acc = 0.f;
    for (int k = 0; k < 128; k += 4) {
        unsigned wp0 = Wbp[(k >> 1) * 64 + j];
        unsigned wp1 = Wbp[((k >> 1) + 1) * 64 + j];
        float4 xv = *(const float4*)&xs[wave][k];
        acc += xv.x * blo(wp0) + xv.y * bhi(wp0) + xv.z * blo(wp1) + xv.w * bhi(wp1);
    }
    g0[(size_t)n * 64 + j] = f2bf(acc);
    if (blockIdx.x == 0 && tid < 16) {
        ((uint2*)(g0 + (size_t)SENT * 64))[tid] = make_uint2(0u, 0u);
    }
}

// ---- 64-d aggregate (32-row chunks): out_row(n) = in_row(n) + sum_neighbors -> bf16 ----
__global__ __launch_bounds__(256, 4) void agg64b(const uint4* __restrict__ tb4,
                                                 const int* __restrict__ cnt,
                                                 const unsigned short* __restrict__ colbuf,
                                                 unsigned short* __restrict__ tb2) {
    constexpr int M = 4;
    const int base = blockIdx.x * M;
    const int tid = threadIdx.x;
    const int wave = tid >> 6;
    const int lane = tid & 63;
    const int sub = lane >> 3;     // 0..7 : 8 rows per load instruction
    const int off = lane & 7;      // 16B slice within a 128B row

    const int n = __builtin_amdgcn_readfirstlane(base + wave);
    float a0, a1, a2, a3, a4, a5, a6, a7;
    if (sub == 0) {                // own row (eps=0)
        uint4 u = tb4[n * 8 + off];
        a0 = blo(u.x); a1 = bhi(u.x); a2 = blo(u.y); a3 = bhi(u.y);
        a4 = blo(u.z); a5 = bhi(u.z); a6 = blo(u.w); a7 = bhi(u.w);
    } else {
        a0 = a1 = a2 = a3 = a4 = a5 = a6 = a7 = 0.f;
    }
    const int NCH = __builtin_amdgcn_readfirstlane(cnt[n]) >> 5;   // 32-row chunks
    const uint2* cl = (const uint2*)(colbuf + (size_t)n * CAP);
    const int hi4 = sub >> 2;
    const int wsel = (sub >> 1) & 1;
    const int sh = (sub & 1) << 4;
    uint2 p0 = cl[0], p1 = cl[1], p2 = cl[2], p3 = cl[3];
    uint2 p4 = cl[4], p5 = cl[5], p6 = cl[6], p7 = cl[7];
    for (int c = 0; c < NCH; ++c) {
        unsigned q0 = hi4 ? (wsel ? p1.y : p1.x) : (wsel ? p0.y : p0.x);
        unsigned q1 = hi4 ? (wsel ? p3.y : p3.x) : (wsel ? p2.y : p2.x);
        unsigned q2 = hi4 ? (wsel ? p5.y : p5.x) : (wsel ? p4.y : p4.x);
        unsigned q3 = hi4 ? (wsel ? p7.y : p7.x) : (wsel ? p6.y : p6.x);
        int s0 = (int)((q0 >> sh) & 0xffffu);
        int s1 = (int)((q1 >> sh) & 0xffffu);
        int s2 = (int)((q2 >> sh) & 0xffffu);
        int s3 = (int)((q3 >> sh) & 0xffffu);
        uint4 u0 = tb4[s0 * 8 + off];
        uint4 u1 = tb4[s1 * 8 + off];
        uint4 u2 = tb4[s2 * 8 + off];
        uint4 u3 = tb4[s3 * 8 + off];
        {
            const uint2* nx = cl + 8 * (c + 1);   // safe over-read within workspace
            p0 = nx[0]; p1 = nx[1]; p2 = nx[2]; p3 = nx[3];
            p4 = nx[4]; p5 = nx[5]; p6 = nx[6]; p7 = nx[7];
        }
        a0 += (blo(u0.x) + blo(u1.x)) + (blo(u2.x) + blo(u3.x));
        a1 += (bhi(u0.x) + bhi(u1.x)) + (bhi(u2.x) + bhi(u3.x));
        a2 += (blo(u0.y) + blo(u1.y)) + (blo(u2.y) + blo(u3.y));
        a3 += (bhi(u0.y) + bhi(u1.y)) + (bhi(u2.y) + bhi(u3.y));
        a4 += (blo(u0.z) + blo(u1.z)) + (blo(u2.z) + blo(u3.z));
        a5 += (bhi(u0.z) + bhi(u1.z)) + (bhi(u2.z) + bhi(u3.z));
        a6 += (blo(u0.w) + blo(u1.w)) + (blo(u2.w) + blo(u3.w));
        a7 += (bhi(u0.w) + bhi(u1.w)) + (bhi(u2.w) + bhi(u3.w));
    }
    a0 += __shfl_xor(a0, 8); a0 += __shfl_xor(a0, 16); a0 += __shfl_xor(a0, 32);
    a1 += __shfl_xor(a1, 8); a1 += __shfl_xor(a1, 16); a1 += __shfl_xor(a1, 32);
    a2 += __shfl_xor(a2, 8); a2 += __shfl_xor(a2, 16); a2 += __shfl_xor(a2, 32);
    a3 += __shfl_xor(a3, 8); a3 += __shfl_xor(a3, 16); a3 += __shfl_xor(a3, 32);
    a4 += __shfl_xor(a4, 8); a4 += __shfl_xor(a4, 16); a4 += __shfl_xor(a4, 32);
    a5 += __shfl_xor(a5, 8); a5 += __shfl_xor(a5, 16); a5 += __shfl_xor(a5, 32);
    a6 += __shfl_xor(a6, 8); a6 += __shfl_xor(a6, 16); a6 += __shfl_xor(a6, 32);
    a7 += __shfl_xor(a7, 8); a7 += __shfl_xor(a7, 16); a7 += __shfl_xor(a7, 32);
    if (sub == 0) {
        unsigned short* o = tb2 + (size_t)n * 64 + 8 * off;
        *(uint4*)o = make_uint4(packbf(a0, a1), packbf(a2, a3),
                                packbf(a4, a5), packbf(a6, a7));
    }
    if (blockIdx.x == 0 && tid < 16) {
        ((uint2*)(tb2 + (size_t)SENT * 64))[tid] = make_uint2(0u, 0u);
    }
}

// ---- final 64-d aggregate (32-row chunks): f32 output ----
__global__ __launch_bounds__(256, 4) void agg64f(const uint4* __restrict__ tb4,
                                                 const int* __restrict__ cnt,
                                                 const unsigned short* __restrict__ colbuf,
                                                 float* __restrict__ outf) {
    constexpr int M = 4;
    const int base = blockIdx.x * M;
    const int tid = threadIdx.x;
    const int wave = tid >> 6;
    const int lane = tid & 63;
    const int sub = lane >> 3;
    const int off = lane & 7;

    const int n = __builtin_amdgcn_readfirstlane(base + wave);
    float a0, a1, a2, a3, a4, a5, a6, a7;
    if (sub == 0) {
        uint4 u = tb4[n * 8 + off];
        a0 = blo(u.x); a1 = bhi(u.x); a2 = blo(u.y); a3 = bhi(u.y);
        a4 = blo(u.z); a5 = bhi(u.z); a6 = blo(u.w); a7 = bhi(u.w);
    } else {
        a0 = a1 = a2 = a3 = a4 = a5 = a6 = a7 = 0.f;
    }
    const int NCH = __builtin_amdgcn_readfirstlane(cnt[n]) >> 5;
    const uint2* cl = (const uint2*)(colbuf + (size_t)n * CAP);
    const int hi4 = sub >> 2;
    const int wsel = (sub >> 1) & 1;
    const int sh = (sub & 1) << 4;
    uint2 p0 = cl[0], p1 = cl[1], p2 = cl[2], p3 = cl[3];
    uint2 p4 = cl[4], p5 = cl[5], p6 = cl[6], p7 = cl[7];
    for (int c = 0; c < NCH; ++c) {
        unsigned q0 = hi4 ? (wsel ? p1.y : p1.x) : (wsel ? p0.y : p0.x);
        unsigned q1 = hi4 ? (wsel ? p3.y : p3.x) : (wsel ? p2.y : p2.x);
        unsigned q2 = hi4 ? (wsel ? p5.y : p5.x) : (wsel ? p4.y : p4.x);
        unsigned q3 = hi4 ? (wsel ? p7.y : p7.x) : (wsel ? p6.y : p6.x);
        int s0 = (int)((q0 >> sh) & 0xffffu);
        int s1 = (int)((q1 >> sh) & 0xffffu);
        int s2 = (int)((q2 >> sh) & 0xffffu);
        int s3 = (int)((q3 >> sh) & 0xffffu);
        uint4 u0 = tb4[s0 * 8 + off];
        uint4 u1 = tb4[s1 * 8 + off];
        uint4 u2 = tb4[s2 * 8 + off];
        uint4 u3 = tb4[s3 * 8 + off];
        {
            const uint2* nx = cl + 8 * (c + 1);
            p0 = nx[0]; p1 = nx[1]; p2 = nx[2]; p3 = nx[3];
            p4 = nx[4]; p5 = nx[5]; p6 = nx[6]; p7 = nx[7];
        }
        a0 += (blo(u0.x) + blo(u1.x)) + (blo(u2.x) + blo(u3.x));
        a1 += (bhi(u0.x) + bhi(u1.x)) + (bhi(u2.x) + bhi(u3.x));
        a2 += (blo(u0.y) + blo(u1.y)) + (blo(u2.y) + blo(u3.y));
        a3 += (bhi(u0.y) + bhi(u1.y)) + (bhi(u2.y) + bhi(u3.y));
        a4 += (blo(u0.z) + blo(u1.z)) + (blo(u2.z) + blo(u3.z));
        a5 += (bhi(u0.z) + bhi(u1.z)) + (bhi(u2.z) + bhi(u3.z));
        a6 += (blo(u0.w) + blo(u1.w)) + (blo(u2.w) + blo(u3.w));
        a7 += (bhi(u0.w) + bhi(u1.w)) + (bhi(u2.w) + bhi(u3.w));
    }
    a0 += __shfl_xor(a0, 8); a0 += __shfl_xor(a0, 16); a0 += __shfl_xor(a0, 32);
    a1 += __shfl_xor(a1, 8); a1 += __shfl_xor(a1, 16); a1 += __shfl_xor(a1, 32);
    a2 += __shfl_xor(a2, 8); a2 += __shfl_xor(a2, 16); a2 += __shfl_xor(a2, 32);
    a3 += __shfl_xor(a3, 8); a3 += __shfl_xor(a3, 16); a3 += __shfl_xor(a3, 32);
    a4 += __shfl_xor(a4, 8); a4 += __shfl_xor(a4, 16); a4 += __shfl_xor(a4, 32);
    a5 += __shfl_xor(a5, 8); a5 += __shfl_xor(a5, 16); a5 += __shfl_xor(a5, 32);
    a6 += __shfl_xor(a6, 8); a6 += __shfl_xor(a6, 16); a6 += __shfl_xor(a6, 32);
    a7 += __shfl_xor(a7, 8); a7 += __shfl_xor(a7, 16); a7 += __shfl_xor(a7, 32);
    if (sub == 0) {
        float* o = outf + (size_t)n * N_CLS + 8 * off;
        *(float4*)o       = make_float4(a0, a1, a2, a3);
        *(float4*)(o + 4) = make_float4(a4, a5, a6, a7);
    }
}

extern "C" void kernel_launch(void* const* d_in, const int* in_sizes, int n_in,
                              void* d_out, int out_size, void* d_ws, size_t ws_size,
                              hipStream_t stream) {
    const float* feat = (const float*)d_in[0];
    const float* W0   = (const float*)d_in[1];
    const float* W1   = (const float*)d_in[2];
    const float* W2   = (const float*)d_in[3];
    const int*   src  = (const int*)d_in[4];
    const int*   dst  = (const int*)d_in[5];
    float* out = (float*)d_out;

    int* coarse_cnt        = (int*)d_ws;                          // GRP*CCS ints
    int* cnt               = coarse_cnt + GRP * CCS;              // NN (+8 align pad)
    unsigned short* colbuf = (unsigned short*)(cnt + NN + 8);     // NN*CAP
    unsigned* coarse       = (unsigned*)(colbuf + (size_t)NN * CAP);  // GRP*CAPC
    unsigned* g0u          = coarse + (size_t)GRP * CAPC;         // (NN+1)*32 (64-d bf16)
    unsigned* tbu          = g0u + (size_t)(NN + 1) * 32;         // (NN+1)*32
    unsigned* tb2u         = tbu + (size_t)(NN + 1) * 32;         // (NN+1)*32
    float* W01             = (float*)(tb2u + (size_t)(NN + 1) * 32); // 16384 f32
    unsigned* wbp          = (unsigned*)(W01 + 16384);            // 4096
    unsigned short* g0     = (unsigned short*)g0u;
    unsigned short* tb     = (unsigned short*)tbu;
    unsigned short* tb2    = (unsigned short*)tb2u;

    (void)hipMemsetAsync(coarse_cnt, 0, GRP * CCS * sizeof(int), stream);
    prep_a<<<AB + W01B, 256, 0, stream>>>(src, dst, coarse_cnt, coarse, W0, W1, W01);
    prep_b<<<GRP + WPB, 1024, 0, stream>>>(coarse_cnt, coarse, cnt, colbuf,
                                           W01, W2, wbp);

    gemm0<<<NN / 4, 256, 0, stream>>>(feat, wbp, g0);
    agg64b<<<NN / 4, 256, 0, stream>>>((const uint4*)g0, cnt, colbuf, tb);
    agg64b<<<NN / 4, 256, 0, stream>>>((const uint4*)tb, cnt, colbuf, tb2);
    agg64f<<<NN / 4, 256, 0, stream>>>((const uint4*)tb2, cnt, colbuf, out);
}